// Round 3
// baseline (141.903 us; speedup 1.0000x reference)
//
#include <hip/hip_runtime.h>

// Problem constants
#define B_   16
#define C_   512
#define N_   1024   // H*W
#define F_   1024
#define T_   180
#define G_   32

// Workspace layout (float offsets)
#define WS_K     0                    // 16384 (B*F)
#define WS_V     16384                // 16384
#define WS_WQS   (2*16384)            // 512
#define WS_WOS   (WS_WQS + 512)       // 512
#define WS_BQS   (WS_WOS + 512)       // 1 (padded to 64)
#define WS_SG    (WS_BQS + 64)        // 512*1024 = 524288  (per-(b,g) S contribution)

// ---------------------------------------------------------------------------
// Kernel 1 (k_w): weight-only precomputation. 69 blocks x 256 threads.
//   blocks [0,64) : K[b,f], V[b,f]   (b = idx>>2, f-chunk = idx&3)
//   blocks 64,65  : WQsum[c] = sum_o wq[o,c]
//   blocks 66,67  : WOsum[o] = sum_c wo[o,c]
//   block  68     : BQsum = sum_c bq[c]
// ---------------------------------------------------------------------------
__global__ __launch_bounds__(256) void k_w(
    const float* __restrict__ cond,
    const float* __restrict__ wq, const float* __restrict__ bq,
    const float* __restrict__ wk, const float* __restrict__ bk,
    const float* __restrict__ wv, const float* __restrict__ bv,
    const float* __restrict__ wo, float* __restrict__ ws)
{
    const int blk = blockIdx.x;
    const int tid = threadIdx.x;

    if (blk < 64) {
        const int b = blk >> 2;
        const int f = ((blk & 3) << 8) + tid;
        __shared__ float condl[T_];
        if (tid < T_) condl[tid] = cond[b * T_ + tid];
        __syncthreads();
        float accK = bk[f];
        float accV = bv[f];
        const float* wkr = wk + f * T_;
        const float* wvr = wv + f * T_;
        #pragma unroll 4
        for (int t = 0; t < T_; ++t) {
            float cf = condl[t];
            accK += cf * wkr[t];
            accV += cf * wvr[t];
        }
        ws[WS_K + b * F_ + f] = accK;
        ws[WS_V + b * F_ + f] = accV;
    } else if (blk < 66) {
        const int c = ((blk - 64) << 8) + tid;
        float acc = 0.f;
        for (int o = 0; o < C_; ++o) acc += wq[o * C_ + c];
        ws[WS_WQS + c] = acc;
    } else if (blk < 68) {
        const int o = ((blk - 66) << 8) + tid;
        const float4* row = (const float4*)(wo + o * C_);
        float acc = 0.f;
        #pragma unroll 8
        for (int j = 0; j < 128; ++j) {
            float4 p = row[j];
            acc += (p.x + p.y) + (p.z + p.w);
        }
        ws[WS_WOS + o] = acc;
    } else {
        float p = bq[tid] + bq[tid + 256];
        #pragma unroll
        for (int off = 32; off; off >>= 1) p += __shfl_down(p, off, 64);
        __shared__ float rb[4];
        if ((tid & 63) == 0) rb[tid >> 6] = p;
        __syncthreads();
        if (tid == 0) ws[WS_BQS] = rb[0] + rb[1] + rb[2] + rb[3];
    }
}

// ---------------------------------------------------------------------------
// Kernel 2 (k_gs): one block per (b,g). Single pass over the 16ch x 1024n slab:
//   mean/rsig AND Sg[b,g,n] = rsig*(P[n] - mu*G1) + G2, where
//   P[n] = sum_{c in g} x[c,n]*gamma_c*WQsum_c, G1 = sum gamma_c*WQsum_c,
//   G2 = sum beta_c*WQsum_c.
// 512 blocks x 256 threads; thread owns 4 consecutive n (float4).
// ---------------------------------------------------------------------------
__global__ __launch_bounds__(256) void k_gs(
    const float* __restrict__ x, const float* __restrict__ gamma,
    const float* __restrict__ beta, float* __restrict__ ws)
{
    const int blk = blockIdx.x;        // b*32 + g
    const int tid = threadIdx.x;

    __shared__ float wl[16], bl[16];
    __shared__ float rs[4], rq[4];
    __shared__ float muS, rsigS;

    if (tid < 16) {
        const int c = ((blk & 31) << 4) + tid;   // global channel
        float wqs = ws[WS_WQS + c];
        wl[tid] = gamma[c] * wqs;
        bl[tid] = beta[c] * wqs;
    }
    __syncthreads();

    const float4* xv = (const float4*)(x + (size_t)blk * 16384);
    float s = 0.f, sq = 0.f;
    float4 acc = make_float4(0.f, 0.f, 0.f, 0.f);
    #pragma unroll
    for (int c = 0; c < 16; ++c) {
        float4 p = xv[(c << 8) + tid];
        s  += (p.x + p.y) + (p.z + p.w);
        sq += p.x * p.x + p.y * p.y + p.z * p.z + p.w * p.w;
        float w = wl[c];
        acc.x += p.x * w; acc.y += p.y * w; acc.z += p.z * w; acc.w += p.w * w;
    }
    #pragma unroll
    for (int off = 32; off; off >>= 1) {
        s  += __shfl_down(s,  off, 64);
        sq += __shfl_down(sq, off, 64);
    }
    if ((tid & 63) == 0) { rs[tid >> 6] = s; rq[tid >> 6] = sq; }
    __syncthreads();
    if (tid == 0) {
        float S1 = rs[0] + rs[1] + rs[2] + rs[3];
        float S2 = rq[0] + rq[1] + rq[2] + rq[3];
        float mu = S1 * (1.f / 16384.f);
        float var = S2 * (1.f / 16384.f) - mu * mu;
        muS = mu;
        rsigS = rsqrtf(var + 1e-6f);
    }
    __syncthreads();

    float G1 = 0.f, G2 = 0.f;
    #pragma unroll
    for (int j = 0; j < 16; ++j) { G1 += wl[j]; G2 += bl[j]; }
    const float rsig = rsigS;
    const float off0 = G2 - rsig * muS * G1;

    float4 sg;
    sg.x = rsig * acc.x + off0;
    sg.y = rsig * acc.y + off0;
    sg.z = rsig * acc.z + off0;
    sg.w = rsig * acc.w + off0;
    ((float4*)(ws + WS_SG + (size_t)blk * N_))[tid] = sg;
}

// ---------------------------------------------------------------------------
// Kernel 3 (k_fused): per (b, 64-n tile):
//   S[n] = BQsum + sum_g Sg[b,g,n]
//   A[n] = sum_f V[b,f]*softmax_f(scale*S[n]*K[b,f])   (analytic max: K extremum)
//   out[b,o,n] = x[b,o,n] + A[n]*WOsum[o] + bo[o]
// 256 blocks = 16 b x 16 n-tiles; 256 threads.
// ---------------------------------------------------------------------------
__global__ __launch_bounds__(256) void k_fused(
    const float* __restrict__ x, const float* __restrict__ bo,
    const float* __restrict__ ws, float* __restrict__ out)
{
    const int b   = blockIdx.x >> 4;
    const int n0  = (blockIdx.x & 15) << 6;
    const int tid = threadIdx.x;

    __shared__ float KV[2 * F_];
    __shared__ float ps[4][64];
    __shared__ float pse[4][64], psv[4][64];
    __shared__ float Sl[64], Al[64];
    __shared__ float redmx[4], redmn[4];

    // ---- Stage K/V interleaved + K extrema ----
    const float* Kg = ws + WS_K + b * F_;
    const float* Vg = ws + WS_V + b * F_;
    float mx = -1e30f, mn = 1e30f;
    #pragma unroll
    for (int i = tid; i < F_; i += 256) {
        float kv = Kg[i];
        KV[2 * i]     = kv;
        KV[2 * i + 1] = Vg[i];
        mx = fmaxf(mx, kv);
        mn = fminf(mn, kv);
    }
    #pragma unroll
    for (int off = 32; off; off >>= 1) {
        mx = fmaxf(mx, __shfl_down(mx, off, 64));
        mn = fminf(mn, __shfl_down(mn, off, 64));
    }
    if ((tid & 63) == 0) { redmx[tid >> 6] = mx; redmn[tid >> 6] = mn; }

    // ---- S[n]: reduce Sg over 32 groups ----
    const int nl = tid & 63, qq = tid >> 6;     // 4 quarters
    {
        const float* sgp = ws + WS_SG + ((size_t)(b * G_ + (qq << 3)) << 10) + n0 + nl;
        float p = 0.f;
        #pragma unroll
        for (int j = 0; j < 8; ++j) p += sgp[(size_t)j << 10];
        ps[qq][nl] = p;
    }
    __syncthreads();
    if (tid < 64) {
        Sl[tid] = ws[WS_BQS] + ps[0][tid] + ps[1][tid] + ps[2][tid] + ps[3][tid];
    }
    __syncthreads();

    const float maxK = fmaxf(fmaxf(redmx[0], redmx[1]), fmaxf(redmx[2], redmx[3]));
    const float minK = fminf(fminf(redmn[0], redmn[1]), fminf(redmn[2], redmn[3]));

    // ---- rank-1 softmax over f ----
    const float LOG2E = 1.4426950408889634f;
    const float scale = 0.044194173824159216f;   // 512^-0.5
    const float s  = Sl[nl] * scale;
    const float sl = s * LOG2E;
    const float ml = (s >= 0.f ? maxK : minK) * sl;   // log2-domain row max

    float se = 0.f, sv = 0.f;
    const int fbase = qq << 8;                   // 256 f per quarter
    #pragma unroll 8
    for (int fi = 0; fi < 256; ++fi) {
        const int f = fbase + fi;
        float kf = KV[2 * f];
        float vf = KV[2 * f + 1];
        float e = exp2f(fmaf(sl, kf, -ml));
        se += e;
        sv = fmaf(vf, e, sv);
    }
    pse[qq][nl] = se;
    psv[qq][nl] = sv;
    __syncthreads();
    if (tid < 64) {
        float den = pse[0][tid] + pse[1][tid] + pse[2][tid] + pse[3][tid];
        float num = psv[0][tid] + psv[1][tid] + psv[2][tid] + psv[3][tid];
        Al[tid] = num / den;
    }
    __syncthreads();

    // ---- residual + projected-out write (float4 along n) ----
    const int col = tid & 15;   // n4-group: n-offset col*4  (16*4 = 64 n)
    const int row = tid >> 4;   // 0..15
    float av[4];
    #pragma unroll
    for (int j = 0; j < 4; ++j) av[j] = Al[(col << 2) + j];
    const float* WOS = ws + WS_WOS;

    for (int p = 0; p < 32; ++p) {
        const int o = (p << 4) + row;
        const float w   = WOS[o];
        const float bof = bo[o];
        const size_t base = (((size_t)(b * C_ + o)) << 10) + n0 + (col << 2);
        float4 xv = *(const float4*)(x + base);
        float4 ov;
        ov.x = xv.x + fmaf(av[0], w, bof);
        ov.y = xv.y + fmaf(av[1], w, bof);
        ov.z = xv.z + fmaf(av[2], w, bof);
        ov.w = xv.w + fmaf(av[3], w, bof);
        *(float4*)(out + base) = ov;
    }
}

extern "C" void kernel_launch(void* const* d_in, const int* in_sizes, int n_in,
                              void* d_out, int out_size, void* d_ws, size_t ws_size,
                              hipStream_t stream) {
    const float* x     = (const float*)d_in[0];
    const float* cond  = (const float*)d_in[1];
    const float* gamma = (const float*)d_in[2];
    const float* beta  = (const float*)d_in[3];
    const float* wq    = (const float*)d_in[4];
    const float* bq    = (const float*)d_in[5];
    const float* wk    = (const float*)d_in[6];
    const float* bk    = (const float*)d_in[7];
    const float* wv    = (const float*)d_in[8];
    const float* bv    = (const float*)d_in[9];
    const float* wo    = (const float*)d_in[10];
    const float* bo    = (const float*)d_in[11];
    float* ws  = (float*)d_ws;
    float* out = (float*)d_out;

    hipLaunchKernelGGL(k_w, dim3(69), dim3(256), 0, stream,
                       cond, wq, bq, wk, bk, wv, bv, wo, ws);
    hipLaunchKernelGGL(k_gs, dim3(512), dim3(256), 0, stream,
                       x, gamma, beta, ws);
    hipLaunchKernelGGL(k_fused, dim3(256), dim3(256), 0, stream,
                       x, bo, ws, out);
}